// Round 1
// baseline (1383.417 us; speedup 1.0000x reference)
//
#include <hip/hip_runtime.h>
#include <hip/hip_bf16.h>
#include <stdint.h>

#define N_NODES   100000
#define N_EDGES   1600000
#define NODE_DIM  128
#define EDGE_DIM  48
#define GLOBAL_DIM 64
#define HIDDEN    256
#define KDIM      256      // 240 padded to 256
#define OUT_DIM   128

#define AGG_BYTES  (N_NODES * EDGE_DIM * 4)          // 19,200,000
#define W1P_BYTES  (KDIM * HIDDEN * 2)               // 131,072
#define W2P_BYTES  (HIDDEN * OUT_DIM * 2)            // 65,536

typedef short  short4_t  __attribute__((ext_vector_type(4)));
typedef short  short8_t  __attribute__((ext_vector_type(8)));
typedef float  floatx4   __attribute__((ext_vector_type(4)));

__device__ __forceinline__ short f2bf(float f) {
    union { float f; uint32_t u; } x; x.f = f;
    uint32_t r = (x.u + 0x7FFFu + ((x.u >> 16) & 1u)) >> 16;   // RNE
    return (short)r;
}

// ---------------- W1 pack: [240,256] f32 -> bf16 B-frag layout, K padded to 256
// dest[((kg*16 + nt)*64 + lane)*8 + j] = W1[kg*32 + (lane>>4)*8 + j][nt*16 + (lane&15)]
__global__ void pack_w1(const float* __restrict__ W1, short* __restrict__ dst) {
    int tid = blockIdx.x * 256 + threadIdx.x;      // 65536 threads
    int k = tid >> 8, n = tid & 255;
    float v = (k < 240) ? W1[k * 256 + n] : 0.0f;
    int kg = k >> 5, kr = k & 31, quad = kr >> 3, j = kr & 7;
    int nt = n >> 4, nl = n & 15, lane = (quad << 4) | nl;
    dst[(((kg * 16 + nt) * 64) + lane) * 8 + j] = f2bf(v);
}

// ---------------- W2 pack: [256,128] f32 -> bf16 B-frag layout
__global__ void pack_w2(const float* __restrict__ W2, short* __restrict__ dst) {
    int tid = blockIdx.x * 256 + threadIdx.x;      // 32768 threads
    int k = tid >> 7, n = tid & 127;
    float v = W2[k * 128 + n];
    int kg = k >> 5, kr = k & 31, quad = kr >> 3, j = kr & 7;
    int nt = n >> 4, nl = n & 15, lane = (quad << 4) | nl;
    dst[(((kg * 8 + nt) * 64) + lane) * 8 + j] = f2bf(v);
}

// ---------------- scatter-add edges -> agg, float4 per thread
__global__ void scatter_edges(const float4* __restrict__ edges4,
                              const int* __restrict__ recv,
                              float* __restrict__ agg) {
    int tid = blockIdx.x * 256 + threadIdx.x;      // 19,200,000 threads exactly
    int e = tid / 12;
    int c = tid - e * 12;
    float4 v = edges4[tid];
    int r = recv[e];
    float* dst = agg + (size_t)r * 48 + c * 4;
    unsafeAtomicAdd(dst + 0, v.x);
    unsafeAtomicAdd(dst + 1, v.y);
    unsafeAtomicAdd(dst + 2, v.z);
    unsafeAtomicAdd(dst + 3, v.w);
}

// ---------------- fused MLP: x=[nodes|agg|u|pad] @ W1 -> relu -> @ W2 + b2
#define LDS_W 264   // 256 + 8 pad: 2-way bank aliasing only (free)
__global__ __launch_bounds__(256, 2)
void mlp_kernel(const float* __restrict__ nodes,
                const float* __restrict__ agg,
                const int* __restrict__ batch,
                const float* __restrict__ gg,
                const short8_t* __restrict__ w1p,
                const short8_t* __restrict__ w2p,
                const float* __restrict__ b1,
                const float* __restrict__ b2,
                float* __restrict__ out) {
    __shared__ short xt[64 * LDS_W];   // 33,792 B; reused for h after layer 1

    const int t = threadIdx.x;
    const int m0 = blockIdx.x * 64;

    // ---- stage x tile as bf16 into LDS ----
    const float4* nodes4 = (const float4*)nodes;
    const float4* agg4   = (const float4*)agg;
    const float4* gg4    = (const float4*)gg;

    // nodes region: cols 0..127 = 32 float4/row, 2048 total, 8/thread
    #pragma unroll
    for (int i = 0; i < 8; ++i) {
        int f = t + 256 * i;
        int r = f >> 5, c4 = f & 31;
        int node = m0 + r;
        float4 v = make_float4(0.f, 0.f, 0.f, 0.f);
        if (node < N_NODES) v = nodes4[node * 32 + c4];
        short4_t s; s.x = f2bf(v.x); s.y = f2bf(v.y); s.z = f2bf(v.z); s.w = f2bf(v.w);
        *(short4_t*)(&xt[r * LDS_W + c4 * 4]) = s;
    }
    // agg region: cols 128..175 = 12 float4/row, 768 total, 3/thread
    #pragma unroll
    for (int i = 0; i < 3; ++i) {
        int f = t + 256 * i;
        int r = f / 12, c4 = f - r * 12;
        int node = m0 + r;
        float4 v = make_float4(0.f, 0.f, 0.f, 0.f);
        if (node < N_NODES) v = agg4[node * 12 + c4];
        short4_t s; s.x = f2bf(v.x); s.y = f2bf(v.y); s.z = f2bf(v.z); s.w = f2bf(v.w);
        *(short4_t*)(&xt[r * LDS_W + (32 + c4) * 4]) = s;
    }
    // globals region: cols 176..239 = 16 float4/row, 1024 total, 4/thread
    #pragma unroll
    for (int i = 0; i < 4; ++i) {
        int f = t + 256 * i;
        int r = f >> 4, c4 = f & 15;
        int node = m0 + r;
        float4 v = make_float4(0.f, 0.f, 0.f, 0.f);
        if (node < N_NODES) { int g = batch[node]; v = gg4[g * 16 + c4]; }
        short4_t s; s.x = f2bf(v.x); s.y = f2bf(v.y); s.z = f2bf(v.z); s.w = f2bf(v.w);
        *(short4_t*)(&xt[r * LDS_W + (44 + c4) * 4]) = s;
    }
    // K-pad region: cols 240..255, 256 float4, 1/thread
    {
        int r = t >> 2, c4 = t & 3;
        short4_t s; s.x = 0; s.y = 0; s.z = 0; s.w = 0;
        *(short4_t*)(&xt[r * LDS_W + (60 + c4) * 4]) = s;
    }
    __syncthreads();

    const int w    = t >> 6;
    const int lane = t & 63;
    const int q    = lane >> 4;
    const int ln   = lane & 15;

    // ---- layer 1: [64x256] x [256x256] -> h, each wave owns 64 cols ----
    floatx4 acc[4][4];
    #pragma unroll
    for (int a = 0; a < 4; ++a)
        #pragma unroll
        for (int b = 0; b < 4; ++b) acc[a][b] = 0.0f;

    #pragma unroll
    for (int kg = 0; kg < 8; ++kg) {
        short8_t A[4], B[4];
        #pragma unroll
        for (int mt = 0; mt < 4; ++mt)
            A[mt] = *(const short8_t*)(&xt[(mt * 16 + ln) * LDS_W + kg * 32 + q * 8]);
        #pragma unroll
        for (int ntl = 0; ntl < 4; ++ntl) {
            int nt = w * 4 + ntl;
            B[ntl] = (const short8_t&)w1p[(kg * 16 + nt) * 64 + lane];
        }
        #pragma unroll
        for (int mt = 0; mt < 4; ++mt)
            #pragma unroll
            for (int ntl = 0; ntl < 4; ++ntl)
                acc[mt][ntl] = __builtin_amdgcn_mfma_f32_16x16x32_bf16(
                    A[mt], B[ntl], acc[mt][ntl], 0, 0, 0);
    }

    float b1v[4];
    #pragma unroll
    for (int ntl = 0; ntl < 4; ++ntl) b1v[ntl] = b1[w * 64 + ntl * 16 + ln];

    __syncthreads();   // everyone done reading x before overwriting with h

    #pragma unroll
    for (int mt = 0; mt < 4; ++mt)
        #pragma unroll
        for (int ntl = 0; ntl < 4; ++ntl)
            #pragma unroll
            for (int r = 0; r < 4; ++r) {
                float v = acc[mt][ntl][r] + b1v[ntl];
                v = fmaxf(v, 0.0f);
                xt[(mt * 16 + q * 4 + r) * LDS_W + w * 64 + ntl * 16 + ln] = f2bf(v);
            }
    __syncthreads();

    // ---- layer 2: [64x256] x [256x128] -> out, each wave owns 32 cols ----
    floatx4 acc2[4][2];
    #pragma unroll
    for (int a = 0; a < 4; ++a)
        #pragma unroll
        for (int b = 0; b < 2; ++b) acc2[a][b] = 0.0f;

    #pragma unroll
    for (int kg = 0; kg < 8; ++kg) {
        short8_t A[4], B[2];
        #pragma unroll
        for (int mt = 0; mt < 4; ++mt)
            A[mt] = *(const short8_t*)(&xt[(mt * 16 + ln) * LDS_W + kg * 32 + q * 8]);
        #pragma unroll
        for (int ntl = 0; ntl < 2; ++ntl) {
            int nt = w * 2 + ntl;
            B[ntl] = (const short8_t&)w2p[(kg * 8 + nt) * 64 + lane];
        }
        #pragma unroll
        for (int mt = 0; mt < 4; ++mt)
            #pragma unroll
            for (int ntl = 0; ntl < 2; ++ntl)
                acc2[mt][ntl] = __builtin_amdgcn_mfma_f32_16x16x32_bf16(
                    A[mt], B[ntl], acc2[mt][ntl], 0, 0, 0);
    }

    float b2v[2];
    #pragma unroll
    for (int ntl = 0; ntl < 2; ++ntl) b2v[ntl] = b2[w * 32 + ntl * 16 + ln];

    #pragma unroll
    for (int mt = 0; mt < 4; ++mt)
        #pragma unroll
        for (int ntl = 0; ntl < 2; ++ntl)
            #pragma unroll
            for (int r = 0; r < 4; ++r) {
                int node = m0 + mt * 16 + q * 4 + r;
                if (node < N_NODES)
                    out[node * 128 + w * 32 + ntl * 16 + ln] = acc2[mt][ntl][r] + b2v[ntl];
            }
}

extern "C" void kernel_launch(void* const* d_in, const int* in_sizes, int n_in,
                              void* d_out, int out_size, void* d_ws, size_t ws_size,
                              hipStream_t stream) {
    const float* nodes = (const float*)d_in[0];
    const float4* edges4 = (const float4*)d_in[1];
    const int* edge_index = (const int*)d_in[2];
    const int* batch = (const int*)d_in[3];
    const float* gg = (const float*)d_in[4];
    const float* W1 = (const float*)d_in[5];
    const float* b1 = (const float*)d_in[6];
    const float* W2 = (const float*)d_in[7];
    const float* b2 = (const float*)d_in[8];
    float* out = (float*)d_out;

    char* ws = (char*)d_ws;
    float* agg = (float*)ws;
    short* w1p = (short*)(ws + AGG_BYTES);
    short* w2p = (short*)(ws + AGG_BYTES + W1P_BYTES);
    const int* recv = edge_index + N_EDGES;   // row 1 of edge_index

    hipMemsetAsync(agg, 0, AGG_BYTES, stream);
    pack_w1<<<256, 256, 0, stream>>>(W1, w1p);
    pack_w2<<<128, 256, 0, stream>>>(W2, w2p);
    scatter_edges<<<(N_EDGES * 12) / 256, 256, 0, stream>>>(edges4, recv, agg);
    mlp_kernel<<<(N_NODES + 63) / 64, 256, 0, stream>>>(
        nodes, agg, batch, gg,
        (const short8_t*)w1p, (const short8_t*)w2p, b1, b2, out);
}

// Round 2
// 762.902 us; speedup vs baseline: 1.8134x; 1.8134x over previous
//
#include <hip/hip_runtime.h>
#include <hip/hip_bf16.h>
#include <stdint.h>

#define N_NODES   100000
#define N_EDGES   1600000
#define NODE_DIM  128
#define EDGE_DIM  48
#define GLOBAL_DIM 64
#define HIDDEN    256
#define KDIM      256      // 240 padded to 256
#define OUT_DIM   128

#define N_PAD     100352   // 98 * 1024, scan-friendly padding of N_NODES
#define SCAN_BLKS 98

// workspace layout (bytes)
#define AGG_OFF   0
#define AGG_BYTES (N_NODES * EDGE_DIM * 4)            // 19,200,000
#define W1P_OFF   (AGG_OFF + AGG_BYTES)
#define W1P_BYTES (KDIM * HIDDEN * 2)                 // 131,072
#define W2P_OFF   (W1P_OFF + W1P_BYTES)
#define W2P_BYTES (HIDDEN * OUT_DIM * 2)              // 65,536
#define CNT_OFF   (W2P_OFF + W2P_BYTES)
#define CNT_BYTES (N_PAD * 4)                         // 401,408
#define OFF_OFF   (CNT_OFF + CNT_BYTES)
#define CUR_OFF   (OFF_OFF + CNT_BYTES)
#define BSUM_OFF  (CUR_OFF + CNT_BYTES)
#define BSUM_BYTES 512
#define BEX_OFF   (BSUM_OFF + BSUM_BYTES)
#define EIDS_OFF  (BEX_OFF + BSUM_BYTES)

typedef short  short4_t  __attribute__((ext_vector_type(4)));
typedef short  short8_t  __attribute__((ext_vector_type(8)));
typedef float  floatx4   __attribute__((ext_vector_type(4)));

__device__ __forceinline__ short f2bf(float f) {
    union { float f; uint32_t u; } x; x.f = f;
    uint32_t r = (x.u + 0x7FFFu + ((x.u >> 16) & 1u)) >> 16;   // RNE
    return (short)r;
}

// ---------------- W1 pack: [240,256] f32 -> bf16 B-frag layout, K padded to 256
__global__ void pack_w1(const float* __restrict__ W1, short* __restrict__ dst) {
    int tid = blockIdx.x * 256 + threadIdx.x;      // 65536 threads
    int k = tid >> 8, n = tid & 255;
    float v = (k < 240) ? W1[k * 256 + n] : 0.0f;
    int kg = k >> 5, kr = k & 31, quad = kr >> 3, j = kr & 7;
    int nt = n >> 4, nl = n & 15, lane = (quad << 4) | nl;
    dst[(((kg * 16 + nt) * 64) + lane) * 8 + j] = f2bf(v);
}

// ---------------- W2 pack: [256,128] f32 -> bf16 B-frag layout
__global__ void pack_w2(const float* __restrict__ W2, short* __restrict__ dst) {
    int tid = blockIdx.x * 256 + threadIdx.x;      // 32768 threads
    int k = tid >> 7, n = tid & 127;
    float v = W2[k * 128 + n];
    int kg = k >> 5, kr = k & 31, quad = kr >> 3, j = kr & 7;
    int nt = n >> 4, nl = n & 15, lane = (quad << 4) | nl;
    dst[(((kg * 8 + nt) * 64) + lane) * 8 + j] = f2bf(v);
}

// ---------------- CSR build ----------------
__global__ void count_kernel(const int* __restrict__ recv, int* __restrict__ cnt) {
    int e = blockIdx.x * 256 + threadIdx.x;
    if (e < N_EDGES) atomicAdd(&cnt[recv[e]], 1);
}

__global__ void scan_bsum(const int4* __restrict__ cnt4, int* __restrict__ bsum) {
    int4 v = cnt4[blockIdx.x * 256 + threadIdx.x];
    int s = v.x + v.y + v.z + v.w;
    #pragma unroll
    for (int d = 32; d; d >>= 1) s += __shfl_down(s, d);
    __shared__ int ws[4];
    if ((threadIdx.x & 63) == 0) ws[threadIdx.x >> 6] = s;
    __syncthreads();
    if (threadIdx.x == 0) bsum[blockIdx.x] = ws[0] + ws[1] + ws[2] + ws[3];
}

__global__ void scan_top(const int* __restrict__ bsum, int* __restrict__ bex) {
    // 1 block, 128 threads: exclusive scan of SCAN_BLKS block sums
    __shared__ int tmp[128];
    int t = threadIdx.x;
    int v = (t < SCAN_BLKS) ? bsum[t] : 0;
    tmp[t] = v;
    __syncthreads();
    #pragma unroll
    for (int d = 1; d < 128; d <<= 1) {
        int add = (t >= d) ? tmp[t - d] : 0;
        __syncthreads();
        tmp[t] += add;
        __syncthreads();
    }
    if (t < SCAN_BLKS) bex[t] = tmp[t] - v;
}

__global__ void scan_write(const int4* __restrict__ cnt4, const int* __restrict__ bex,
                           int4* __restrict__ off4, int4* __restrict__ cur4) {
    int t = threadIdx.x, b = blockIdx.x;
    int4 v = cnt4[b * 256 + t];
    int tsum = v.x + v.y + v.z + v.w;
    int lane = t & 63, w = t >> 6;
    // inclusive wave scan of tsum
    int x = tsum;
    #pragma unroll
    for (int d = 1; d < 64; d <<= 1) {
        int y = __shfl_up(x, d);
        if (lane >= d) x += y;
    }
    __shared__ int wsum[4];
    if (lane == 63) wsum[w] = x;
    __syncthreads();
    int wb = 0;
    if (w > 0) wb += wsum[0];
    if (w > 1) wb += wsum[1];
    if (w > 2) wb += wsum[2];
    int base = bex[b] + wb + (x - tsum);   // exclusive prefix for this thread
    int4 o;
    o.x = base;
    o.y = base + v.x;
    o.z = base + v.x + v.y;
    o.w = base + v.x + v.y + v.z;
    off4[b * 256 + t] = o;
    cur4[b * 256 + t] = o;
}

__global__ void fill_kernel(const int* __restrict__ recv, int* __restrict__ cur,
                            int* __restrict__ eids) {
    int e = blockIdx.x * 256 + threadIdx.x;
    if (e < N_EDGES) {
        int pos = atomicAdd(&cur[recv[e]], 1);
        eids[pos] = e;
    }
}

// ---------------- gather: one wave per node, lanes 0..47 own one column
__global__ __launch_bounds__(256)
void gather_kernel(const float* __restrict__ edges, const int* __restrict__ eids,
                   const int* __restrict__ off, const int* __restrict__ cnt,
                   float* __restrict__ agg) {
    int node = blockIdx.x * 4 + (threadIdx.x >> 6);
    int lane = threadIdx.x & 63;
    if (node >= N_NODES) return;
    int o = off[node], c = cnt[node];
    float acc = 0.0f;
    int i = 0;
    for (; i + 4 <= c; i += 4) {
        int e0 = eids[o + i + 0];
        int e1 = eids[o + i + 1];
        int e2 = eids[o + i + 2];
        int e3 = eids[o + i + 3];
        if (lane < 48) {
            float v0 = edges[(size_t)e0 * 48 + lane];
            float v1 = edges[(size_t)e1 * 48 + lane];
            float v2 = edges[(size_t)e2 * 48 + lane];
            float v3 = edges[(size_t)e3 * 48 + lane];
            acc += (v0 + v1) + (v2 + v3);
        }
    }
    for (; i < c; ++i) {
        int e = eids[o + i];
        if (lane < 48) acc += edges[(size_t)e * 48 + lane];
    }
    if (lane < 48) agg[(size_t)node * 48 + lane] = acc;
}

// ---------------- fused MLP: x=[nodes|agg|u|pad] @ W1 -> relu -> @ W2 + b2
#define LDS_W 264   // 256 + 8 pad: 2-way bank aliasing only (free)
__global__ __launch_bounds__(256, 2)
void mlp_kernel(const float* __restrict__ nodes,
                const float* __restrict__ agg,
                const int* __restrict__ batch,
                const float* __restrict__ gg,
                const short8_t* __restrict__ w1p,
                const short8_t* __restrict__ w2p,
                const float* __restrict__ b1,
                const float* __restrict__ b2,
                float* __restrict__ out) {
    __shared__ short xt[64 * LDS_W];   // 33,792 B; reused for h after layer 1

    const int t = threadIdx.x;
    const int m0 = blockIdx.x * 64;

    const float4* nodes4 = (const float4*)nodes;
    const float4* agg4   = (const float4*)agg;
    const float4* gg4    = (const float4*)gg;

    #pragma unroll
    for (int i = 0; i < 8; ++i) {
        int f = t + 256 * i;
        int r = f >> 5, c4 = f & 31;
        int node = m0 + r;
        float4 v = make_float4(0.f, 0.f, 0.f, 0.f);
        if (node < N_NODES) v = nodes4[node * 32 + c4];
        short4_t s; s.x = f2bf(v.x); s.y = f2bf(v.y); s.z = f2bf(v.z); s.w = f2bf(v.w);
        *(short4_t*)(&xt[r * LDS_W + c4 * 4]) = s;
    }
    #pragma unroll
    for (int i = 0; i < 3; ++i) {
        int f = t + 256 * i;
        int r = f / 12, c4 = f - r * 12;
        int node = m0 + r;
        float4 v = make_float4(0.f, 0.f, 0.f, 0.f);
        if (node < N_NODES) v = agg4[node * 12 + c4];
        short4_t s; s.x = f2bf(v.x); s.y = f2bf(v.y); s.z = f2bf(v.z); s.w = f2bf(v.w);
        *(short4_t*)(&xt[r * LDS_W + (32 + c4) * 4]) = s;
    }
    #pragma unroll
    for (int i = 0; i < 4; ++i) {
        int f = t + 256 * i;
        int r = f >> 4, c4 = f & 15;
        int node = m0 + r;
        float4 v = make_float4(0.f, 0.f, 0.f, 0.f);
        if (node < N_NODES) { int g = batch[node]; v = gg4[g * 16 + c4]; }
        short4_t s; s.x = f2bf(v.x); s.y = f2bf(v.y); s.z = f2bf(v.z); s.w = f2bf(v.w);
        *(short4_t*)(&xt[r * LDS_W + (44 + c4) * 4]) = s;
    }
    {
        int r = t >> 2, c4 = t & 3;
        short4_t s; s.x = 0; s.y = 0; s.z = 0; s.w = 0;
        *(short4_t*)(&xt[r * LDS_W + (60 + c4) * 4]) = s;
    }
    __syncthreads();

    const int w    = t >> 6;
    const int lane = t & 63;
    const int q    = lane >> 4;
    const int ln   = lane & 15;

    // ---- layer 1: [64x256] x [256x256] -> h, each wave owns 64 cols ----
    floatx4 acc[4][4];
    #pragma unroll
    for (int a = 0; a < 4; ++a)
        #pragma unroll
        for (int b = 0; b < 4; ++b) acc[a][b] = 0.0f;

    #pragma unroll
    for (int kg = 0; kg < 8; ++kg) {
        short8_t A[4], B[4];
        #pragma unroll
        for (int mt = 0; mt < 4; ++mt)
            A[mt] = *(const short8_t*)(&xt[(mt * 16 + ln) * LDS_W + kg * 32 + q * 8]);
        #pragma unroll
        for (int ntl = 0; ntl < 4; ++ntl) {
            int nt = w * 4 + ntl;
            B[ntl] = (const short8_t&)w1p[(kg * 16 + nt) * 64 + lane];
        }
        #pragma unroll
        for (int mt = 0; mt < 4; ++mt)
            #pragma unroll
            for (int ntl = 0; ntl < 4; ++ntl)
                acc[mt][ntl] = __builtin_amdgcn_mfma_f32_16x16x32_bf16(
                    A[mt], B[ntl], acc[mt][ntl], 0, 0, 0);
    }

    float b1v[4];
    #pragma unroll
    for (int ntl = 0; ntl < 4; ++ntl) b1v[ntl] = b1[w * 64 + ntl * 16 + ln];

    __syncthreads();

    #pragma unroll
    for (int mt = 0; mt < 4; ++mt)
        #pragma unroll
        for (int ntl = 0; ntl < 4; ++ntl)
            #pragma unroll
            for (int r = 0; r < 4; ++r) {
                float v = acc[mt][ntl][r] + b1v[ntl];
                v = fmaxf(v, 0.0f);
                xt[(mt * 16 + q * 4 + r) * LDS_W + w * 64 + ntl * 16 + ln] = f2bf(v);
            }
    __syncthreads();

    // ---- layer 2: [64x256] x [256x128] -> out, each wave owns 32 cols ----
    floatx4 acc2[4][2];
    #pragma unroll
    for (int a = 0; a < 4; ++a)
        #pragma unroll
        for (int b = 0; b < 2; ++b) acc2[a][b] = 0.0f;

    #pragma unroll
    for (int kg = 0; kg < 8; ++kg) {
        short8_t A[4], B[2];
        #pragma unroll
        for (int mt = 0; mt < 4; ++mt)
            A[mt] = *(const short8_t*)(&xt[(mt * 16 + ln) * LDS_W + kg * 32 + q * 8]);
        #pragma unroll
        for (int ntl = 0; ntl < 2; ++ntl) {
            int nt = w * 2 + ntl;
            B[ntl] = (const short8_t&)w2p[(kg * 8 + nt) * 64 + lane];
        }
        #pragma unroll
        for (int mt = 0; mt < 4; ++mt)
            #pragma unroll
            for (int ntl = 0; ntl < 2; ++ntl)
                acc2[mt][ntl] = __builtin_amdgcn_mfma_f32_16x16x32_bf16(
                    A[mt], B[ntl], acc2[mt][ntl], 0, 0, 0);
    }

    float b2v[2];
    #pragma unroll
    for (int ntl = 0; ntl < 2; ++ntl) b2v[ntl] = b2[w * 32 + ntl * 16 + ln];

    #pragma unroll
    for (int mt = 0; mt < 4; ++mt)
        #pragma unroll
        for (int ntl = 0; ntl < 2; ++ntl)
            #pragma unroll
            for (int r = 0; r < 4; ++r) {
                int node = m0 + mt * 16 + q * 4 + r;
                if (node < N_NODES)
                    out[node * 128 + w * 32 + ntl * 16 + ln] = acc2[mt][ntl][r] + b2v[ntl];
            }
}

extern "C" void kernel_launch(void* const* d_in, const int* in_sizes, int n_in,
                              void* d_out, int out_size, void* d_ws, size_t ws_size,
                              hipStream_t stream) {
    const float* nodes = (const float*)d_in[0];
    const float* edges = (const float*)d_in[1];
    const int* edge_index = (const int*)d_in[2];
    const int* batch = (const int*)d_in[3];
    const float* gg = (const float*)d_in[4];
    const float* W1 = (const float*)d_in[5];
    const float* b1 = (const float*)d_in[6];
    const float* W2 = (const float*)d_in[7];
    const float* b2 = (const float*)d_in[8];
    float* out = (float*)d_out;

    char* ws = (char*)d_ws;
    float* agg  = (float*)(ws + AGG_OFF);
    short* w1p  = (short*)(ws + W1P_OFF);
    short* w2p  = (short*)(ws + W2P_OFF);
    int*   cnt  = (int*)  (ws + CNT_OFF);
    int*   off  = (int*)  (ws + OFF_OFF);
    int*   cur  = (int*)  (ws + CUR_OFF);
    int*   bsum = (int*)  (ws + BSUM_OFF);
    int*   bex  = (int*)  (ws + BEX_OFF);
    int*   eids = (int*)  (ws + EIDS_OFF);
    const int* recv = edge_index + N_EDGES;   // row 1 of edge_index

    hipMemsetAsync(cnt, 0, CNT_BYTES, stream);
    pack_w1<<<256, 256, 0, stream>>>(W1, w1p);
    pack_w2<<<128, 256, 0, stream>>>(W2, w2p);
    count_kernel<<<(N_EDGES + 255) / 256, 256, 0, stream>>>(recv, cnt);
    scan_bsum<<<SCAN_BLKS, 256, 0, stream>>>((const int4*)cnt, bsum);
    scan_top<<<1, 128, 0, stream>>>(bsum, bex);
    scan_write<<<SCAN_BLKS, 256, 0, stream>>>((const int4*)cnt, bex, (int4*)off, (int4*)cur);
    fill_kernel<<<(N_EDGES + 255) / 256, 256, 0, stream>>>(recv, cur, eids);
    gather_kernel<<<(N_NODES + 3) / 4, 256, 0, stream>>>(edges, eids, off, cnt, agg);
    mlp_kernel<<<(N_NODES + 63) / 64, 256, 0, stream>>>(
        nodes, agg, batch, gg,
        (const short8_t*)w1p, (const short8_t*)w2p, b1, b2, out);
}

// Round 3
// 742.623 us; speedup vs baseline: 1.8629x; 1.0273x over previous
//
#include <hip/hip_runtime.h>
#include <hip/hip_bf16.h>
#include <stdint.h>

#define N_NODES   100000
#define N_EDGES   1600000
#define NODE_DIM  128
#define EDGE_DIM  48
#define GLOBAL_DIM 64
#define HIDDEN    256
#define KDIM      256      // 240 padded to 256
#define OUT_DIM   128

#define N_PAD     100352   // 98 * 1024, scan-friendly padding of N_NODES
#define SCAN_BLKS 98

// workspace layout (bytes) — all offsets 16B-aligned
#define W1P_OFF   0
#define W1P_BYTES (KDIM * HIDDEN * 2)                 // 131,072
#define W2P_OFF   (W1P_OFF + W1P_BYTES)
#define W2P_BYTES (HIDDEN * OUT_DIM * 2)              // 65,536
#define CNT_OFF   (W2P_OFF + W2P_BYTES)
#define CNT_BYTES (N_PAD * 4)                         // 401,408
#define OFF_OFF   (CNT_OFF + CNT_BYTES)
#define BSUM_OFF  (OFF_OFF + CNT_BYTES)
#define BSUM_BYTES 512
#define BEX_OFF   (BSUM_OFF + BSUM_BYTES)
#define RANK_OFF  (BEX_OFF + BSUM_BYTES)
#define RANK_BYTES (N_EDGES * 4)                      // 6,400,000
#define EIDS_OFF  (RANK_OFF + RANK_BYTES)

typedef short  short4_t  __attribute__((ext_vector_type(4)));
typedef short  short8_t  __attribute__((ext_vector_type(8)));
typedef float  floatx4   __attribute__((ext_vector_type(4)));

__device__ __forceinline__ short f2bf(float f) {
    union { float f; uint32_t u; } x; x.f = f;
    uint32_t r = (x.u + 0x7FFFu + ((x.u >> 16) & 1u)) >> 16;   // RNE
    return (short)r;
}

// ---------------- W1 pack: [240,256] f32 -> bf16 B-frag layout, K padded to 256
__global__ void pack_w1(const float* __restrict__ W1, short* __restrict__ dst) {
    int tid = blockIdx.x * 256 + threadIdx.x;      // 65536 threads
    int k = tid >> 8, n = tid & 255;
    float v = (k < 240) ? W1[k * 256 + n] : 0.0f;
    int kg = k >> 5, kr = k & 31, quad = kr >> 3, j = kr & 7;
    int nt = n >> 4, nl = n & 15, lane = (quad << 4) | nl;
    dst[(((kg * 16 + nt) * 64) + lane) * 8 + j] = f2bf(v);
}

// ---------------- W2 pack: [256,128] f32 -> bf16 B-frag layout
__global__ void pack_w2(const float* __restrict__ W2, short* __restrict__ dst) {
    int tid = blockIdx.x * 256 + threadIdx.x;      // 32768 threads
    int k = tid >> 7, n = tid & 127;
    float v = W2[k * 128 + n];
    int kg = k >> 5, kr = k & 31, quad = kr >> 3, j = kr & 7;
    int nt = n >> 4, nl = n & 15, lane = (quad << 4) | nl;
    dst[(((kg * 8 + nt) * 64) + lane) * 8 + j] = f2bf(v);
}

// ---------------- CSR build ----------------
// count + rank in one pass: rank[e] = this edge's slot within its node
__global__ void count_kernel(const int4* __restrict__ recv4, int* __restrict__ cnt,
                             int4* __restrict__ rank4) {
    int tid = blockIdx.x * 256 + threadIdx.x;
    if (tid >= N_EDGES / 4) return;
    int4 r = recv4[tid];
    int4 k;
    k.x = atomicAdd(&cnt[r.x], 1);
    k.y = atomicAdd(&cnt[r.y], 1);
    k.z = atomicAdd(&cnt[r.z], 1);
    k.w = atomicAdd(&cnt[r.w], 1);
    rank4[tid] = k;
}

__global__ void scan_bsum(const int4* __restrict__ cnt4, int* __restrict__ bsum) {
    int4 v = cnt4[blockIdx.x * 256 + threadIdx.x];
    int s = v.x + v.y + v.z + v.w;
    #pragma unroll
    for (int d = 32; d; d >>= 1) s += __shfl_down(s, d);
    __shared__ int ws[4];
    if ((threadIdx.x & 63) == 0) ws[threadIdx.x >> 6] = s;
    __syncthreads();
    if (threadIdx.x == 0) bsum[blockIdx.x] = ws[0] + ws[1] + ws[2] + ws[3];
}

__global__ void scan_top(const int* __restrict__ bsum, int* __restrict__ bex) {
    __shared__ int tmp[128];
    int t = threadIdx.x;
    int v = (t < SCAN_BLKS) ? bsum[t] : 0;
    tmp[t] = v;
    __syncthreads();
    #pragma unroll
    for (int d = 1; d < 128; d <<= 1) {
        int add = (t >= d) ? tmp[t - d] : 0;
        __syncthreads();
        tmp[t] += add;
        __syncthreads();
    }
    if (t < SCAN_BLKS) bex[t] = tmp[t] - v;
}

__global__ void scan_write(const int4* __restrict__ cnt4, const int* __restrict__ bex,
                           int4* __restrict__ off4) {
    int t = threadIdx.x, b = blockIdx.x;
    int4 v = cnt4[b * 256 + t];
    int tsum = v.x + v.y + v.z + v.w;
    int lane = t & 63, w = t >> 6;
    int x = tsum;
    #pragma unroll
    for (int d = 1; d < 64; d <<= 1) {
        int y = __shfl_up(x, d);
        if (lane >= d) x += y;
    }
    __shared__ int wsum[4];
    if (lane == 63) wsum[w] = x;
    __syncthreads();
    int wb = 0;
    if (w > 0) wb += wsum[0];
    if (w > 1) wb += wsum[1];
    if (w > 2) wb += wsum[2];
    int base = bex[b] + wb + (x - tsum);
    int4 o;
    o.x = base;
    o.y = base + v.x;
    o.z = base + v.x + v.y;
    o.w = base + v.x + v.y + v.z;
    off4[b * 256 + t] = o;
}

// atomic-free fill: eids[off[recv[e]] + rank[e]] = e
__global__ void fill_kernel(const int4* __restrict__ recv4, const int4* __restrict__ rank4,
                            const int* __restrict__ off, int* __restrict__ eids) {
    int tid = blockIdx.x * 256 + threadIdx.x;
    if (tid >= N_EDGES / 4) return;
    int4 r = recv4[tid];
    int4 k = rank4[tid];
    int e = tid * 4;
    eids[off[r.x] + k.x] = e + 0;
    eids[off[r.y] + k.y] = e + 1;
    eids[off[r.z] + k.z] = e + 2;
    eids[off[r.w] + k.w] = e + 3;
}

// ---------------- fused gather + MLP ----------------
// Per block: 64 nodes. Gather phase: each wave owns 16 nodes, processed as
// 4 quads; lanes 0..47 = (sub=lane/12)*12 + c4, sub-node's row read as 12
// float4 lanes; f32 accumulate in registers -> bf16 straight into LDS x-tile.
#define LDS_W 264   // 256 + 8 pad
__global__ __launch_bounds__(256, 2)
void mlp_kernel(const float* __restrict__ nodes,
                const int* __restrict__ eids,
                const int* __restrict__ off,
                const float4* __restrict__ edges4,
                const int* __restrict__ batch,
                const float* __restrict__ gg,
                const short8_t* __restrict__ w1p,
                const short8_t* __restrict__ w2p,
                const float* __restrict__ b1,
                const float* __restrict__ b2,
                float* __restrict__ out) {
    __shared__ short xt[64 * LDS_W];   // reused for h after layer 1

    const int t = threadIdx.x;
    const int m0 = blockIdx.x * 64;
    const int w    = t >> 6;
    const int lane = t & 63;

    // ---- gather edges -> agg region of LDS (cols 128..175) ----
    {
        int sub = lane / 12;             // 0..3 active, 4..5 idle
        int c4g = lane - sub * 12;       // 0..11
        bool gact = lane < 48;
        #pragma unroll
        for (int qi = 0; qi < 4; ++qi) {
            int r = w * 16 + qi * 4 + sub;   // row in tile (when gact)
            int node = m0 + r;
            int o = 0, c = 0;
            if (gact && node < N_NODES) {
                o = off[node];
                c = off[node + 1] - o;
            }
            int cmax = c;
            #pragma unroll
            for (int d = 1; d < 64; d <<= 1) cmax = max(cmax, __shfl_xor(cmax, d));
            float4 acc = make_float4(0.f, 0.f, 0.f, 0.f);
            int i = 0;
            for (; i + 2 <= cmax; i += 2) {
                float4 v0 = make_float4(0.f, 0.f, 0.f, 0.f);
                float4 v1 = make_float4(0.f, 0.f, 0.f, 0.f);
                if (i < c) {
                    int e0 = eids[o + i];
                    v0 = edges4[(size_t)e0 * 12 + c4g];
                }
                if (i + 1 < c) {
                    int e1 = eids[o + i + 1];
                    v1 = edges4[(size_t)e1 * 12 + c4g];
                }
                acc.x += v0.x + v1.x; acc.y += v0.y + v1.y;
                acc.z += v0.z + v1.z; acc.w += v0.w + v1.w;
            }
            if (i < cmax && i < c) {
                int e0 = eids[o + i];
                float4 v0 = edges4[(size_t)e0 * 12 + c4g];
                acc.x += v0.x; acc.y += v0.y; acc.z += v0.z; acc.w += v0.w;
            }
            if (gact) {
                short4_t s;
                s.x = f2bf(acc.x); s.y = f2bf(acc.y);
                s.z = f2bf(acc.z); s.w = f2bf(acc.w);
                *(short4_t*)(&xt[r * LDS_W + (32 + c4g) * 4]) = s;
            }
        }
    }

    // ---- stage nodes (cols 0..127), globals (176..239), pad (240..255) ----
    const float4* nodes4 = (const float4*)nodes;
    const float4* gg4    = (const float4*)gg;

    #pragma unroll
    for (int i = 0; i < 8; ++i) {
        int f = t + 256 * i;
        int r = f >> 5, c4 = f & 31;
        int node = m0 + r;
        float4 v = make_float4(0.f, 0.f, 0.f, 0.f);
        if (node < N_NODES) v = nodes4[node * 32 + c4];
        short4_t s; s.x = f2bf(v.x); s.y = f2bf(v.y); s.z = f2bf(v.z); s.w = f2bf(v.w);
        *(short4_t*)(&xt[r * LDS_W + c4 * 4]) = s;
    }
    #pragma unroll
    for (int i = 0; i < 4; ++i) {
        int f = t + 256 * i;
        int r = f >> 4, c4 = f & 15;
        int node = m0 + r;
        float4 v = make_float4(0.f, 0.f, 0.f, 0.f);
        if (node < N_NODES) { int g = batch[node]; v = gg4[g * 16 + c4]; }
        short4_t s; s.x = f2bf(v.x); s.y = f2bf(v.y); s.z = f2bf(v.z); s.w = f2bf(v.w);
        *(short4_t*)(&xt[r * LDS_W + (44 + c4) * 4]) = s;
    }
    {
        int r = t >> 2, c4 = t & 3;
        short4_t s; s.x = 0; s.y = 0; s.z = 0; s.w = 0;
        *(short4_t*)(&xt[r * LDS_W + (60 + c4) * 4]) = s;
    }
    __syncthreads();

    const int q  = lane >> 4;
    const int ln = lane & 15;

    // ---- layer 1: [64x256] x [256x256] -> h ----
    floatx4 acc[4][4];
    #pragma unroll
    for (int a = 0; a < 4; ++a)
        #pragma unroll
        for (int b = 0; b < 4; ++b) acc[a][b] = 0.0f;

    #pragma unroll
    for (int kg = 0; kg < 8; ++kg) {
        short8_t A[4], B[4];
        #pragma unroll
        for (int mt = 0; mt < 4; ++mt)
            A[mt] = *(const short8_t*)(&xt[(mt * 16 + ln) * LDS_W + kg * 32 + q * 8]);
        #pragma unroll
        for (int ntl = 0; ntl < 4; ++ntl) {
            int nt = w * 4 + ntl;
            B[ntl] = (const short8_t&)w1p[(kg * 16 + nt) * 64 + lane];
        }
        #pragma unroll
        for (int mt = 0; mt < 4; ++mt)
            #pragma unroll
            for (int ntl = 0; ntl < 4; ++ntl)
                acc[mt][ntl] = __builtin_amdgcn_mfma_f32_16x16x32_bf16(
                    A[mt], B[ntl], acc[mt][ntl], 0, 0, 0);
    }

    float b1v[4];
    #pragma unroll
    for (int ntl = 0; ntl < 4; ++ntl) b1v[ntl] = b1[w * 64 + ntl * 16 + ln];

    __syncthreads();

    #pragma unroll
    for (int mt = 0; mt < 4; ++mt)
        #pragma unroll
        for (int ntl = 0; ntl < 4; ++ntl)
            #pragma unroll
            for (int r = 0; r < 4; ++r) {
                float v = acc[mt][ntl][r] + b1v[ntl];
                v = fmaxf(v, 0.0f);
                xt[(mt * 16 + q * 4 + r) * LDS_W + w * 64 + ntl * 16 + ln] = f2bf(v);
            }
    __syncthreads();

    // ---- layer 2: [64x256] x [256x128] -> out ----
    floatx4 acc2[4][2];
    #pragma unroll
    for (int a = 0; a < 4; ++a)
        #pragma unroll
        for (int b = 0; b < 2; ++b) acc2[a][b] = 0.0f;

    #pragma unroll
    for (int kg = 0; kg < 8; ++kg) {
        short8_t A[4], B[2];
        #pragma unroll
        for (int mt = 0; mt < 4; ++mt)
            A[mt] = *(const short8_t*)(&xt[(mt * 16 + ln) * LDS_W + kg * 32 + q * 8]);
        #pragma unroll
        for (int ntl = 0; ntl < 2; ++ntl) {
            int nt = w * 2 + ntl;
            B[ntl] = (const short8_t&)w2p[(kg * 8 + nt) * 64 + lane];
        }
        #pragma unroll
        for (int mt = 0; mt < 4; ++mt)
            #pragma unroll
            for (int ntl = 0; ntl < 2; ++ntl)
                acc2[mt][ntl] = __builtin_amdgcn_mfma_f32_16x16x32_bf16(
                    A[mt], B[ntl], acc2[mt][ntl], 0, 0, 0);
    }

    float b2v[2];
    #pragma unroll
    for (int ntl = 0; ntl < 2; ++ntl) b2v[ntl] = b2[w * 32 + ntl * 16 + ln];

    #pragma unroll
    for (int mt = 0; mt < 4; ++mt)
        #pragma unroll
        for (int ntl = 0; ntl < 2; ++ntl)
            #pragma unroll
            for (int r = 0; r < 4; ++r) {
                int node = m0 + mt * 16 + q * 4 + r;
                if (node < N_NODES)
                    out[node * 128 + w * 32 + ntl * 16 + ln] = acc2[mt][ntl][r] + b2v[ntl];
            }
}

extern "C" void kernel_launch(void* const* d_in, const int* in_sizes, int n_in,
                              void* d_out, int out_size, void* d_ws, size_t ws_size,
                              hipStream_t stream) {
    const float* nodes = (const float*)d_in[0];
    const float* edges = (const float*)d_in[1];
    const int* edge_index = (const int*)d_in[2];
    const int* batch = (const int*)d_in[3];
    const float* gg = (const float*)d_in[4];
    const float* W1 = (const float*)d_in[5];
    const float* b1 = (const float*)d_in[6];
    const float* W2 = (const float*)d_in[7];
    const float* b2 = (const float*)d_in[8];
    float* out = (float*)d_out;

    char* ws = (char*)d_ws;
    short* w1p  = (short*)(ws + W1P_OFF);
    short* w2p  = (short*)(ws + W2P_OFF);
    int*   cnt  = (int*)  (ws + CNT_OFF);
    int*   off  = (int*)  (ws + OFF_OFF);
    int*   bsum = (int*)  (ws + BSUM_OFF);
    int*   bex  = (int*)  (ws + BEX_OFF);
    int*   rank = (int*)  (ws + RANK_OFF);
    int*   eids = (int*)  (ws + EIDS_OFF);
    const int* recv = edge_index + N_EDGES;   // row 1 of edge_index

    hipMemsetAsync(cnt, 0, CNT_BYTES, stream);
    pack_w1<<<256, 256, 0, stream>>>(W1, w1p);
    pack_w2<<<128, 256, 0, stream>>>(W2, w2p);
    count_kernel<<<(N_EDGES / 4 + 255) / 256, 256, 0, stream>>>(
        (const int4*)recv, cnt, (int4*)rank);
    scan_bsum<<<SCAN_BLKS, 256, 0, stream>>>((const int4*)cnt, bsum);
    scan_top<<<1, 128, 0, stream>>>(bsum, bex);
    scan_write<<<SCAN_BLKS, 256, 0, stream>>>((const int4*)cnt, bex, (int4*)off);
    fill_kernel<<<(N_EDGES / 4 + 255) / 256, 256, 0, stream>>>(
        (const int4*)recv, (const int4*)rank, off, eids);
    mlp_kernel<<<(N_NODES + 63) / 64, 256, 0, stream>>>(
        nodes, eids, off, (const float4*)edges, batch, gg,
        (const short8_t*)w1p, (const short8_t*)w2p, b1, b2, out);
}